// Round 2
// baseline (714.555 us; speedup 1.0000x reference)
//
#include <hip/hip_runtime.h>
#include <hip/hip_bf16.h>
#include <stdint.h>

// ---------- bf16 helpers (bit-level, RNE) ----------
__device__ __forceinline__ float bf2f(unsigned short u) {
    return __uint_as_float(((unsigned int)u) << 16);
}
__device__ __forceinline__ unsigned short f2bf(float f) {
    unsigned int x = __float_as_uint(f);
    unsigned int r = (x + 0x7fffu + ((x >> 16) & 1u)) >> 16;
    return (unsigned short)r;
}

typedef __attribute__((ext_vector_type(8))) __bf16 bf16x8;
typedef __attribute__((ext_vector_type(4))) float f32x4;

__device__ __forceinline__ void gload_lds16(const void* g, void* l) {
    __builtin_amdgcn_global_load_lds(
        (const __attribute__((address_space(1))) unsigned int*)g,
        (__attribute__((address_space(3))) unsigned int*)l,
        16, 0, 0);
}

// ---------- cast fp32 -> bf16 (vectorized) ----------
__global__ void cast_to_bf16(const float4* __restrict__ in,
                             ushort4* __restrict__ out, int n4) {
    int i = blockIdx.x * blockDim.x + threadIdx.x;
    if (i < n4) {
        float4 v = in[i];
        ushort4 o;
        o.x = f2bf(v.x); o.y = f2bf(v.y); o.z = f2bf(v.z); o.w = f2bf(v.w);
        out[i] = o;
    }
}

// ---------- bf16 GEMM: C[M,N] = A[M,K] * B[N,K]^T + bias ----------
// A row-major [M,K] bf16, B row-major [N,K] bf16 (weights as given).
// Output bf16 (Obf) or fp32 (Of32); bias0/bias1 optional fp32 [N].
// M % 128 == 0, N % 128 == 0, K % 64 == 0.
__global__ __launch_bounds__(256, 2)
void gemm_bt(const unsigned short* __restrict__ A,
             const unsigned short* __restrict__ B,
             unsigned short* __restrict__ Obf,
             float* __restrict__ Of32,
             const float* __restrict__ bias0,
             const float* __restrict__ bias1,
             int M, int N, int K)
{
    constexpr int BM = 128, BN = 128, BK = 64;
    __shared__ alignas(16) unsigned short Al[2][BM][BK]; // 16KB x2
    __shared__ alignas(16) unsigned short Bl[2][BN][BK]; // 16KB x2

    const int tid  = threadIdx.x;
    const int wave = tid >> 6;
    const int lane = tid & 63;
    const int wr   = wave >> 1;       // wave row (0..1)
    const int wc   = wave & 1;        // wave col (0..1)
    // grid: x = N tiles (fast-varying -> A-panel L2 reuse), y = M tiles
    const int n0 = blockIdx.x * BN;
    const int m0 = blockIdx.y * BM;

    const int lrow = lane >> 3;        // 0..7 rows within an 8-row stripe
    const int lcol = (lane & 7) * 8;   // bf16 element offset (16B chunks)

    auto stage = [&](int buf, int kt) {
        const int k0 = kt * BK;
#pragma unroll
        for (int r = 0; r < 4; ++r) {
            const int srow = wave * 32 + r * 8;
            gload_lds16(A + (size_t)(m0 + srow + lrow) * K + k0 + lcol,
                        &Al[buf][srow][0]);
            gload_lds16(B + (size_t)(n0 + srow + lrow) * K + k0 + lcol,
                        &Bl[buf][srow][0]);
        }
    };

    f32x4 acc[4][4] = {};

    const int nt = K / BK;
    stage(0, 0);
    for (int kt = 0; kt < nt; ++kt) {
        const int cur = kt & 1;
        __syncthreads();                    // tile kt ready (vmcnt drained at barrier)
        if (kt + 1 < nt) stage(cur ^ 1, kt + 1);

        const int ra = wr * 64 + (lane & 15);
        const int rb = wc * 64 + (lane & 15);
#pragma unroll
        for (int kk = 0; kk < BK; kk += 32) {
            const int ko = kk + (lane >> 4) * 8;
            bf16x8 af[4], bfr[4];
#pragma unroll
            for (int m = 0; m < 4; ++m)
                af[m] = *(const bf16x8*)&Al[cur][ra + m * 16][ko];
#pragma unroll
            for (int n = 0; n < 4; ++n)
                bfr[n] = *(const bf16x8*)&Bl[cur][rb + n * 16][ko];
#pragma unroll
            for (int m = 0; m < 4; ++m)
#pragma unroll
                for (int n = 0; n < 4; ++n)
                    acc[m][n] = __builtin_amdgcn_mfma_f32_16x16x32_bf16(
                        af[m], bfr[n], acc[m][n], 0, 0, 0);
        }
    }

    // epilogue: C/D layout col = lane&15, row = (lane>>4)*4 + i  [m89/m91 verified]
    const int colb = n0 + wc * 64;
    const int rowb = m0 + wr * 64 + (lane >> 4) * 4;
#pragma unroll
    for (int n = 0; n < 4; ++n) {
        const int col = colb + n * 16 + (lane & 15);
        float bs = 0.f;
        if (bias0) bs += bias0[col];
        if (bias1) bs += bias1[col];
#pragma unroll
        for (int m = 0; m < 4; ++m) {
#pragma unroll
            for (int i = 0; i < 4; ++i) {
                const int row = rowb + m * 16 + i;
                const float v = acc[m][n][i] + bs;
                if (Obf) Obf[(size_t)row * N + col] = f2bf(v);
                else     Of32[(size_t)row * N + col] = v;
            }
        }
    }
}

// ---------- IndRNN scan: h_t = relu(p_t + u * h_{t-1}) along T ----------
// proj bf16 [Bc,T,H] -> hout bf16 (may alias proj; in-place safe: each thread
// reads/writes only its own (b,h) column). Software-pipelined loads.
__global__ __launch_bounds__(256)
void indrnn_scan(const unsigned short* __restrict__ proj,
                 const float* __restrict__ u,
                 unsigned short* __restrict__ hout,
                 int T, int H)
{
    const int gid = blockIdx.x * blockDim.x + threadIdx.x;
    const int b   = gid / H;
    const int h   = gid % H;   // lanes -> consecutive h -> coalesced 128B/wave
    const size_t base = (size_t)b * T * H + h;
    const float uu = u[h];
    float hv = 0.f;

    constexpr int U = 16;      // group size; T % (2U) == 0
    float va[U], vb[U];
#pragma unroll
    for (int i = 0; i < U; ++i)
        va[i] = bf2f(proj[base + (size_t)i * H]);

    for (int t0 = 0; t0 < T; t0 += 2 * U) {
        // prefetch group B (t0+U) — always valid since t0 <= T-2U
#pragma unroll
        for (int i = 0; i < U; ++i)
            vb[i] = bf2f(proj[base + (size_t)(t0 + U + i) * H]);
        // compute group A
#pragma unroll
        for (int i = 0; i < U; ++i) {
            hv = fmaf(uu, hv, va[i]);
            hv = hv > 0.f ? hv : 0.f;
            hout[base + (size_t)(t0 + i) * H] = f2bf(hv);
        }
        // prefetch group A for t0+2U
        if (t0 + 2 * U < T) {
#pragma unroll
            for (int i = 0; i < U; ++i)
                va[i] = bf2f(proj[base + (size_t)(t0 + 2 * U + i) * H]);
        }
        // compute group B
#pragma unroll
        for (int i = 0; i < U; ++i) {
            hv = fmaf(uu, hv, vb[i]);
            hv = hv > 0.f ? hv : 0.f;
            hout[base + (size_t)(t0 + U + i) * H] = f2bf(hv);
        }
    }
}

extern "C" void kernel_launch(void* const* d_in, const int* in_sizes, int n_in,
                              void* d_out, int out_size, void* d_ws, size_t ws_size,
                              hipStream_t stream) {
    const float* x   = (const float*)d_in[0];
    const float* W0  = (const float*)d_in[1];
    const float* bl0 = (const float*)d_in[2];
    const float* u0  = (const float*)d_in[3];
    const float* bb0 = (const float*)d_in[4];
    const float* W1  = (const float*)d_in[5];
    const float* bl1 = (const float*)d_in[6];
    const float* u1  = (const float*)d_in[7];
    const float* bb1 = (const float*)d_in[8];
    const float* fcW = (const float*)d_in[9];
    const float* fcb = (const float*)d_in[10];

    const int B = 64, T = 2048, Din = 128, H = 512, Dout = 128;

    // ---- workspace layout (adaptive to ws_size) ----
    const size_t szW0 = (size_t)H * Din * 2;    // 128 KB
    const size_t szW1 = (size_t)H * H * 2;      // 512 KB
    const size_t szFc = (size_t)Dout * H * 2;   // 128 KB
    const size_t wfix = szW0 + szW1 + szFc;

    int Bc = B;
    while (Bc > 1) {
        size_t need = wfix + (size_t)Bc * T * Din * 2  // x chunk bf16
                    + 2 * ((size_t)Bc * T * H * 2);    // two [Mc,H] bf16 bufs
        if (need <= ws_size) break;
        Bc >>= 1;
    }
    const int Mc = Bc * T;

    char* p = (char*)d_ws;
    unsigned short* W0b  = (unsigned short*)p;            p += szW0;
    unsigned short* W1b  = (unsigned short*)p;            p += szW1;
    unsigned short* fcWb = (unsigned short*)p;            p += szFc;
    unsigned short* xc   = (unsigned short*)p;            p += (size_t)Mc * Din * 2;
    unsigned short* buf0 = (unsigned short*)p;            p += (size_t)Mc * H * 2;
    unsigned short* buf1 = (unsigned short*)p;

    // ---- cast weights once ----
    cast_to_bf16<<<(H * Din / 4) / 256, 256, 0, stream>>>((const float4*)W0, (ushort4*)W0b, H * Din / 4);
    cast_to_bf16<<<(H * H / 4) / 256, 256, 0, stream>>>((const float4*)W1, (ushort4*)W1b, H * H / 4);
    cast_to_bf16<<<(Dout * H / 4) / 256, 256, 0, stream>>>((const float4*)fcW, (ushort4*)fcWb, Dout * H / 4);

    const dim3 blk(256);
    for (int b0 = 0; b0 < B; b0 += Bc) {
        const float* xchunk = x + (size_t)b0 * T * Din;
        float* outchunk = (float*)d_out + (size_t)b0 * T * Dout;

        const int n4 = Mc * Din / 4;
        cast_to_bf16<<<n4 / 256, blk, 0, stream>>>((const float4*)xchunk, (ushort4*)xc, n4);

        // layer 0: buf0 = xc @ W0^T + bl0 + bb0
        gemm_bt<<<dim3(H / 128, Mc / 128), blk, 0, stream>>>(
            xc, W0b, buf0, nullptr, bl0, bb0, Mc, H, Din);
        // scan 0 (in-place): buf0 = scan(buf0)
        indrnn_scan<<<dim3(Bc * H / 256), blk, 0, stream>>>(buf0, u0, buf0, T, H);

        // layer 1: buf1 = buf0 @ W1^T + bl1 + bb1
        gemm_bt<<<dim3(H / 128, Mc / 128), blk, 0, stream>>>(
            buf0, W1b, buf1, nullptr, bl1, bb1, Mc, H, H);
        // scan 1 (in-place): buf1 = scan(buf1)
        indrnn_scan<<<dim3(Bc * H / 256), blk, 0, stream>>>(buf1, u1, buf1, T, H);

        // FC: out = buf1 @ fcW^T + fc_b (fp32)
        gemm_bt<<<dim3(Dout / 128, Mc / 128), blk, 0, stream>>>(
            buf1, fcWb, nullptr, outchunk, fcb, nullptr, Mc, Dout, H);
    }
}

// Round 3
// 535.424 us; speedup vs baseline: 1.3346x; 1.3346x over previous
//
#include <hip/hip_runtime.h>
#include <hip/hip_bf16.h>
#include <stdint.h>

// ---------- bf16 helpers (bit-level, RNE) ----------
__device__ __forceinline__ float bf2f(unsigned short u) {
    return __uint_as_float(((unsigned int)u) << 16);
}
__device__ __forceinline__ unsigned short f2bf(float f) {
    unsigned int x = __float_as_uint(f);
    unsigned int r = (x + 0x7fffu + ((x >> 16) & 1u)) >> 16;
    return (unsigned short)r;
}

typedef __attribute__((ext_vector_type(8))) __bf16 bf16x8;
typedef __attribute__((ext_vector_type(4))) float f32x4;

__device__ __forceinline__ void gload_lds16(const void* g, void* l) {
    __builtin_amdgcn_global_load_lds(
        (const __attribute__((address_space(1))) unsigned int*)g,
        (__attribute__((address_space(3))) unsigned int*)l,
        16, 0, 0);
}

// ---------- cast fp32 -> bf16 (vectorized) ----------
__global__ void cast_to_bf16(const float4* __restrict__ in,
                             ushort4* __restrict__ out, int n4) {
    int i = blockIdx.x * blockDim.x + threadIdx.x;
    if (i < n4) {
        float4 v = in[i];
        ushort4 o;
        o.x = f2bf(v.x); o.y = f2bf(v.y); o.z = f2bf(v.z); o.w = f2bf(v.w);
        out[i] = o;
    }
}

// ---------- bf16 GEMM: C[M,N] = A[M,K] * B[N,K]^T + bias ----------
__global__ __launch_bounds__(256, 2)
void gemm_bt(const unsigned short* __restrict__ A,
             const unsigned short* __restrict__ B,
             unsigned short* __restrict__ Obf,
             float* __restrict__ Of32,
             const float* __restrict__ bias0,
             const float* __restrict__ bias1,
             int M, int N, int K)
{
    constexpr int BM = 128, BN = 128, BK = 64;
    __shared__ alignas(16) unsigned short Al[2][BM][BK];
    __shared__ alignas(16) unsigned short Bl[2][BN][BK];

    const int tid  = threadIdx.x;
    const int wave = tid >> 6;
    const int lane = tid & 63;
    const int wr   = wave >> 1;
    const int wc   = wave & 1;
    const int n0 = blockIdx.x * BN;   // x = N tiles fast-varying -> A-panel L2 reuse
    const int m0 = blockIdx.y * BM;

    const int lrow = lane >> 3;
    const int lcol = (lane & 7) * 8;

    auto stage = [&](int buf, int kt) {
        const int k0 = kt * BK;
#pragma unroll
        for (int r = 0; r < 4; ++r) {
            const int srow = wave * 32 + r * 8;
            gload_lds16(A + (size_t)(m0 + srow + lrow) * K + k0 + lcol,
                        &Al[buf][srow][0]);
            gload_lds16(B + (size_t)(n0 + srow + lrow) * K + k0 + lcol,
                        &Bl[buf][srow][0]);
        }
    };

    f32x4 acc[4][4] = {};

    const int nt = K / BK;
    stage(0, 0);
    for (int kt = 0; kt < nt; ++kt) {
        const int cur = kt & 1;
        __syncthreads();
        if (kt + 1 < nt) stage(cur ^ 1, kt + 1);

        const int ra = wr * 64 + (lane & 15);
        const int rb = wc * 64 + (lane & 15);
#pragma unroll
        for (int kk = 0; kk < BK; kk += 32) {
            const int ko = kk + (lane >> 4) * 8;
            bf16x8 af[4], bfr[4];
#pragma unroll
            for (int m = 0; m < 4; ++m)
                af[m] = *(const bf16x8*)&Al[cur][ra + m * 16][ko];
#pragma unroll
            for (int n = 0; n < 4; ++n)
                bfr[n] = *(const bf16x8*)&Bl[cur][rb + n * 16][ko];
#pragma unroll
            for (int m = 0; m < 4; ++m)
#pragma unroll
                for (int n = 0; n < 4; ++n)
                    acc[m][n] = __builtin_amdgcn_mfma_f32_16x16x32_bf16(
                        af[m], bfr[n], acc[m][n], 0, 0, 0);
        }
    }

    const int colb = n0 + wc * 64;
    const int rowb = m0 + wr * 64 + (lane >> 4) * 4;
#pragma unroll
    for (int n = 0; n < 4; ++n) {
        const int col = colb + n * 16 + (lane & 15);
        float bs = 0.f;
        if (bias0) bs += bias0[col];
        if (bias1) bs += bias1[col];
#pragma unroll
        for (int m = 0; m < 4; ++m) {
#pragma unroll
            for (int i = 0; i < 4; ++i) {
                const int row = rowb + m * 16 + i;
                const float v = acc[m][n][i] + bs;
                if (Obf) Obf[(size_t)row * N + col] = f2bf(v);
                else     Of32[(size_t)row * N + col] = v;
            }
        }
    }
}

// ================= segmented parallel IndRNN scan =================
// h_t = relu(p_t + u*h_{t-1}), u >= 0. Composition f(h)=max(C, A + u^L h)
// is associative on h>=0:  C' = max(0, p + u*C), A' = p + u*A.
constexpr int S_SEG = 16;

// pass 1: per-segment (C, A) summary. thread = (b, s, h); consecutive h lanes.
__global__ __launch_bounds__(256)
void scan_pass1(const unsigned short* __restrict__ proj,
                const float* __restrict__ u,
                float* __restrict__ Csum, float* __restrict__ Asum,
                int T, int H)
{
    const int L = T / S_SEG;
    const int gid = blockIdx.x * blockDim.x + threadIdx.x;
    const int h  = gid % H;
    const int bs = gid / H;
    const int s  = bs % S_SEG;
    const int b  = bs / S_SEG;
    const float uu = u[h];
    const unsigned short* p = proj + ((size_t)b * T + (size_t)s * L) * H + h;

    float C = 0.f, A = 0.f;
    constexpr int U = 8;
    float va[U], vb[U];
#pragma unroll
    for (int i = 0; i < U; ++i) va[i] = bf2f(p[(size_t)i * H]);
    for (int t0 = 0; t0 < L; t0 += 2 * U) {
#pragma unroll
        for (int i = 0; i < U; ++i) vb[i] = bf2f(p[(size_t)(t0 + U + i) * H]);
#pragma unroll
        for (int i = 0; i < U; ++i) {
            C = fmaf(uu, C, va[i]); C = C > 0.f ? C : 0.f;
            A = fmaf(uu, A, va[i]);
        }
        if (t0 + 2 * U < L) {
#pragma unroll
            for (int i = 0; i < U; ++i) va[i] = bf2f(p[(size_t)(t0 + 2 * U + i) * H]);
        }
#pragma unroll
        for (int i = 0; i < U; ++i) {
            C = fmaf(uu, C, vb[i]); C = C > 0.f ? C : 0.f;
            A = fmaf(uu, A, vb[i]);
        }
    }
    Csum[gid] = C;
    Asum[gid] = A;
}

// cross-segment serial combine per chain (b,h): h_in for each segment.
__global__ __launch_bounds__(256)
void scan_boundary(const float* __restrict__ Csum, const float* __restrict__ Asum,
                   const float* __restrict__ u,
                   float* __restrict__ hin, int T, int H)
{
    const int gid = blockIdx.x * blockDim.x + threadIdx.x; // b*H + h
    const int h = gid % H;
    const int b = gid / H;
    const int L = T / S_SEG;
    const float W = powf(u[h], (float)L);
    float Cv[S_SEG], Av[S_SEG];
#pragma unroll
    for (int s = 0; s < S_SEG; ++s) {
        Cv[s] = Csum[((size_t)b * S_SEG + s) * H + h];
        Av[s] = Asum[((size_t)b * S_SEG + s) * H + h];
    }
    float hr = 0.f;
#pragma unroll
    for (int s = 0; s < S_SEG; ++s) {
        hin[((size_t)b * S_SEG + s) * H + h] = hr;
        const float t = fmaf(W, hr, Av[s]);
        hr = Cv[s] > t ? Cv[s] : t;
    }
}

// pass 2: re-walk segment from hin, write h (in-place over proj).
__global__ __launch_bounds__(256)
void scan_pass2(unsigned short* __restrict__ proj,
                const float* __restrict__ u,
                const float* __restrict__ hin,
                int T, int H)
{
    const int L = T / S_SEG;
    const int gid = blockIdx.x * blockDim.x + threadIdx.x;
    const int h  = gid % H;
    const int bs = gid / H;
    const int s  = bs % S_SEG;
    const int b  = bs / S_SEG;
    const float uu = u[h];
    unsigned short* p = proj + ((size_t)b * T + (size_t)s * L) * H + h;
    float hv = hin[gid];

    constexpr int U = 8;
    float va[U], vb[U];
#pragma unroll
    for (int i = 0; i < U; ++i) va[i] = bf2f(p[(size_t)i * H]);
    for (int t0 = 0; t0 < L; t0 += 2 * U) {
#pragma unroll
        for (int i = 0; i < U; ++i) vb[i] = bf2f(p[(size_t)(t0 + U + i) * H]);
#pragma unroll
        for (int i = 0; i < U; ++i) {
            hv = fmaf(uu, hv, va[i]);
            hv = hv > 0.f ? hv : 0.f;
            p[(size_t)(t0 + i) * H] = f2bf(hv);
        }
        if (t0 + 2 * U < L) {
#pragma unroll
            for (int i = 0; i < U; ++i) va[i] = bf2f(p[(size_t)(t0 + 2 * U + i) * H]);
        }
#pragma unroll
        for (int i = 0; i < U; ++i) {
            hv = fmaf(uu, hv, vb[i]);
            hv = hv > 0.f ? hv : 0.f;
            p[(size_t)(t0 + U + i) * H] = f2bf(hv);
        }
    }
}

static inline void run_scan(unsigned short* buf, const float* u,
                            float* Csum, float* Asum, float* hin,
                            int Bc, int T, int H, hipStream_t stream) {
    const int nseg = Bc * S_SEG * H;
    scan_pass1<<<nseg / 256, 256, 0, stream>>>(buf, u, Csum, Asum, T, H);
    scan_boundary<<<Bc * H / 256, 256, 0, stream>>>(Csum, Asum, u, hin, T, H);
    scan_pass2<<<nseg / 256, 256, 0, stream>>>(buf, u, hin, T, H);
}

extern "C" void kernel_launch(void* const* d_in, const int* in_sizes, int n_in,
                              void* d_out, int out_size, void* d_ws, size_t ws_size,
                              hipStream_t stream) {
    const float* x   = (const float*)d_in[0];
    const float* W0  = (const float*)d_in[1];
    const float* bl0 = (const float*)d_in[2];
    const float* u0  = (const float*)d_in[3];
    const float* bb0 = (const float*)d_in[4];
    const float* W1  = (const float*)d_in[5];
    const float* bl1 = (const float*)d_in[6];
    const float* u1  = (const float*)d_in[7];
    const float* bb1 = (const float*)d_in[8];
    const float* fcW = (const float*)d_in[9];
    const float* fcb = (const float*)d_in[10];

    const int B = 64, T = 2048, Din = 128, H = 512, Dout = 128;

    const size_t szW0 = (size_t)H * Din * 2;
    const size_t szW1 = (size_t)H * H * 2;
    const size_t szFc = (size_t)Dout * H * 2;
    const size_t wfix = szW0 + szW1 + szFc;

    // layout: [weights][buf0: Bc*T*H bf16][R: Bc*T*H bf16 (xc then buf1)][3 summary planes]
    int Bc = B;
    while (Bc > 1) {
        const size_t szBuf  = (size_t)Bc * T * H * 2;
        const size_t szSumm = 3 * (size_t)Bc * S_SEG * H * 4;
        if (wfix + 2 * szBuf + szSumm <= ws_size) break;
        Bc >>= 1;
    }
    const int Mc = Bc * T;

    char* p = (char*)d_ws;
    unsigned short* W0b  = (unsigned short*)p;  p += szW0;
    unsigned short* W1b  = (unsigned short*)p;  p += szW1;
    unsigned short* fcWb = (unsigned short*)p;  p += szFc;
    unsigned short* buf0 = (unsigned short*)p;  p += (size_t)Mc * H * 2;
    unsigned short* R    = (unsigned short*)p;  p += (size_t)Mc * H * 2; // xc, then buf1
    float* Csum = (float*)p;                    p += (size_t)Bc * S_SEG * H * 4;
    float* Asum = (float*)p;                    p += (size_t)Bc * S_SEG * H * 4;
    float* hin  = (float*)p;

    cast_to_bf16<<<(H * Din / 4) / 256, 256, 0, stream>>>((const float4*)W0, (ushort4*)W0b, H * Din / 4);
    cast_to_bf16<<<(H * H / 4) / 256, 256, 0, stream>>>((const float4*)W1, (ushort4*)W1b, H * H / 4);
    cast_to_bf16<<<(Dout * H / 4) / 256, 256, 0, stream>>>((const float4*)fcW, (ushort4*)fcWb, Dout * H / 4);

    const dim3 blk(256);
    for (int b0 = 0; b0 < B; b0 += Bc) {
        const float* xchunk = x + (size_t)b0 * T * Din;
        float* outchunk = (float*)d_out + (size_t)b0 * T * Dout;
        unsigned short* xc   = R;            // [Mc, Din] bf16
        unsigned short* buf1 = R;            // [Mc, H] bf16 (after xc is dead)

        const int n4 = Mc * Din / 4;
        cast_to_bf16<<<n4 / 256, blk, 0, stream>>>((const float4*)xchunk, (ushort4*)xc, n4);

        // layer 0
        gemm_bt<<<dim3(H / 128, Mc / 128), blk, 0, stream>>>(
            xc, W0b, buf0, nullptr, bl0, bb0, Mc, H, Din);
        run_scan(buf0, u0, Csum, Asum, hin, Bc, T, H, stream);

        // layer 1 (buf1 overwrites xc region; xc dead after GEMM0)
        gemm_bt<<<dim3(H / 128, Mc / 128), blk, 0, stream>>>(
            buf0, W1b, buf1, nullptr, bl1, bb1, Mc, H, H);
        run_scan(buf1, u1, Csum, Asum, hin, Bc, T, H, stream);

        // FC
        gemm_bt<<<dim3(Dout / 128, Mc / 128), blk, 0, stream>>>(
            buf1, fcWb, nullptr, outchunk, fcb, nullptr, Mc, Dout, H);
    }
}

// Round 4
// 511.329 us; speedup vs baseline: 1.3974x; 1.0471x over previous
//
#include <hip/hip_runtime.h>
#include <hip/hip_bf16.h>
#include <stdint.h>

// ---------- bf16 helpers (bit-level, RNE) ----------
__device__ __forceinline__ float bf2f(unsigned short u) {
    return __uint_as_float(((unsigned int)u) << 16);
}
__device__ __forceinline__ unsigned short f2bf(float f) {
    unsigned int x = __float_as_uint(f);
    unsigned int r = (x + 0x7fffu + ((x >> 16) & 1u)) >> 16;
    return (unsigned short)r;
}

typedef __attribute__((ext_vector_type(8))) __bf16 bf16x8;
typedef __attribute__((ext_vector_type(4))) float f32x4;

__device__ __forceinline__ void gload_lds16(const void* g, void* l) {
    __builtin_amdgcn_global_load_lds(
        (const __attribute__((address_space(1))) unsigned int*)g,
        (__attribute__((address_space(3))) unsigned int*)l,
        16, 0, 0);
}

// ---------- cast fp32 -> bf16 (vectorized) ----------
__global__ void cast_to_bf16(const float4* __restrict__ in,
                             ushort4* __restrict__ out, int n4) {
    int i = blockIdx.x * blockDim.x + threadIdx.x;
    if (i < n4) {
        float4 v = in[i];
        ushort4 o;
        o.x = f2bf(v.x); o.y = f2bf(v.y); o.z = f2bf(v.z); o.w = f2bf(v.w);
        out[i] = o;
    }
}

// ---------- bf16 GEMM: C[M,N] = A[M,K] * B[N,K]^T + bias ----------
// BK=32: 64B LDS rows -> bank-quad (row*4+chunk)%8 -> conflict-free fragment
// reads (m97-verified geometry). BK=64 (128B rows) is a 16-way conflict.
__global__ __launch_bounds__(256, 4)
void gemm_bt(const unsigned short* __restrict__ A,
             const unsigned short* __restrict__ B,
             unsigned short* __restrict__ Obf,
             float* __restrict__ Of32,
             const float* __restrict__ bias0,
             const float* __restrict__ bias1,
             int M, int N, int K)
{
    constexpr int BM = 128, BN = 128, BK = 32;
    __shared__ alignas(16) unsigned short Al[2][BM][BK]; // 8KB x2
    __shared__ alignas(16) unsigned short Bl[2][BN][BK]; // 8KB x2

    const int tid  = threadIdx.x;
    const int wave = tid >> 6;
    const int lane = tid & 63;
    const int wr   = wave >> 1;
    const int wc   = wave & 1;

    // XCD-chunk swizzle (bijective; all our grids have nwg % 8 == 0):
    // same-A-panel blocks (consecutive x) land on the same XCD's L2.
    const int nwg = gridDim.x * gridDim.y;
    int lid = blockIdx.y * gridDim.x + blockIdx.x;
    if ((nwg & 7) == 0) lid = (lid & 7) * (nwg >> 3) + (lid >> 3);
    const int n0 = (lid % gridDim.x) * BN;
    const int m0 = (lid / gridDim.x) * BM;

    const int lrow = lane >> 2;        // 0..15 rows per 1KB wave store
    const int lcol = (lane & 3) * 8;   // 4 chunks of 8 bf16 (16B)

    auto stage = [&](int buf, int kt) {
        const int k0 = kt * BK;
#pragma unroll
        for (int r = 0; r < 2; ++r) {
            const int srow = wave * 32 + r * 16;
            gload_lds16(A + (size_t)(m0 + srow + lrow) * K + k0 + lcol,
                        &Al[buf][srow][0]);
            gload_lds16(B + (size_t)(n0 + srow + lrow) * K + k0 + lcol,
                        &Bl[buf][srow][0]);
        }
    };

    f32x4 acc[4][4] = {};

    const int nt = K / BK;
    stage(0, 0);
    for (int kt = 0; kt < nt; ++kt) {
        const int cur = kt & 1;
        __syncthreads();                 // tile kt ready
        if (kt + 1 < nt) stage(cur ^ 1, kt + 1);

        const int ra = wr * 64 + (lane & 15);
        const int rb = wc * 64 + (lane & 15);
        const int ko = (lane >> 4) * 8;
        bf16x8 af[4], bfr[4];
#pragma unroll
        for (int m = 0; m < 4; ++m)
            af[m] = *(const bf16x8*)&Al[cur][ra + m * 16][ko];
#pragma unroll
        for (int n = 0; n < 4; ++n)
            bfr[n] = *(const bf16x8*)&Bl[cur][rb + n * 16][ko];
#pragma unroll
        for (int m = 0; m < 4; ++m)
#pragma unroll
            for (int n = 0; n < 4; ++n)
                acc[m][n] = __builtin_amdgcn_mfma_f32_16x16x32_bf16(
                    af[m], bfr[n], acc[m][n], 0, 0, 0);
    }

    // epilogue: C/D layout col = lane&15, row = (lane>>4)*4 + i
    const int colb = n0 + wc * 64;
    const int rowb = m0 + wr * 64 + (lane >> 4) * 4;
#pragma unroll
    for (int n = 0; n < 4; ++n) {
        const int col = colb + n * 16 + (lane & 15);
        float bs = 0.f;
        if (bias0) bs += bias0[col];
        if (bias1) bs += bias1[col];
#pragma unroll
        for (int m = 0; m < 4; ++m) {
#pragma unroll
            for (int i = 0; i < 4; ++i) {
                const int row = rowb + m * 16 + i;
                const float v = acc[m][n][i] + bs;
                if (Obf) Obf[(size_t)row * N + col] = f2bf(v);
                else     Of32[(size_t)row * N + col] = v;
            }
        }
    }
}

// ================= segmented parallel IndRNN scan =================
// h_t = relu(p_t + u*h_{t-1}), u >= 0. Composition f(h)=max(C, A + u^L h)
// is associative on h>=0:  C' = max(0, p + u*C), A' = p + u*A.
constexpr int S_SEG = 16;

__global__ __launch_bounds__(256)
void scan_pass1(const unsigned short* __restrict__ proj,
                const float* __restrict__ u,
                float* __restrict__ Csum, float* __restrict__ Asum,
                int T, int H)
{
    const int L = T / S_SEG;
    const int gid = blockIdx.x * blockDim.x + threadIdx.x;
    const int h  = gid % H;
    const int bs = gid / H;
    const int s  = bs % S_SEG;
    const int b  = bs / S_SEG;
    const float uu = u[h];
    const unsigned short* p = proj + ((size_t)b * T + (size_t)s * L) * H + h;

    float C = 0.f, A = 0.f;
    constexpr int U = 8;
    float va[U], vb[U];
#pragma unroll
    for (int i = 0; i < U; ++i) va[i] = bf2f(p[(size_t)i * H]);
    for (int t0 = 0; t0 < L; t0 += 2 * U) {
#pragma unroll
        for (int i = 0; i < U; ++i) vb[i] = bf2f(p[(size_t)(t0 + U + i) * H]);
#pragma unroll
        for (int i = 0; i < U; ++i) {
            C = fmaf(uu, C, va[i]); C = C > 0.f ? C : 0.f;
            A = fmaf(uu, A, va[i]);
        }
        if (t0 + 2 * U < L) {
#pragma unroll
            for (int i = 0; i < U; ++i) va[i] = bf2f(p[(size_t)(t0 + 2 * U + i) * H]);
        }
#pragma unroll
        for (int i = 0; i < U; ++i) {
            C = fmaf(uu, C, vb[i]); C = C > 0.f ? C : 0.f;
            A = fmaf(uu, A, vb[i]);
        }
    }
    Csum[gid] = C;
    Asum[gid] = A;
}

__global__ __launch_bounds__(256)
void scan_boundary(const float* __restrict__ Csum, const float* __restrict__ Asum,
                   const float* __restrict__ u,
                   float* __restrict__ hin, int T, int H)
{
    const int gid = blockIdx.x * blockDim.x + threadIdx.x; // b*H + h
    const int h = gid % H;
    const int b = gid / H;
    const int L = T / S_SEG;
    const float W = powf(u[h], (float)L);
    float Cv[S_SEG], Av[S_SEG];
#pragma unroll
    for (int s = 0; s < S_SEG; ++s) {
        Cv[s] = Csum[((size_t)b * S_SEG + s) * H + h];
        Av[s] = Asum[((size_t)b * S_SEG + s) * H + h];
    }
    float hr = 0.f;
#pragma unroll
    for (int s = 0; s < S_SEG; ++s) {
        hin[((size_t)b * S_SEG + s) * H + h] = hr;
        const float t = fmaf(W, hr, Av[s]);
        hr = Cv[s] > t ? Cv[s] : t;
    }
}

__global__ __launch_bounds__(256)
void scan_pass2(unsigned short* __restrict__ proj,
                const float* __restrict__ u,
                const float* __restrict__ hin,
                int T, int H)
{
    const int L = T / S_SEG;
    const int gid = blockIdx.x * blockDim.x + threadIdx.x;
    const int h  = gid % H;
    const int bs = gid / H;
    const int s  = bs % S_SEG;
    const int b  = bs / S_SEG;
    const float uu = u[h];
    unsigned short* p = proj + ((size_t)b * T + (size_t)s * L) * H + h;
    float hv = hin[gid];

    constexpr int U = 8;
    float va[U], vb[U];
#pragma unroll
    for (int i = 0; i < U; ++i) va[i] = bf2f(p[(size_t)i * H]);
    for (int t0 = 0; t0 < L; t0 += 2 * U) {
#pragma unroll
        for (int i = 0; i < U; ++i) vb[i] = bf2f(p[(size_t)(t0 + U + i) * H]);
#pragma unroll
        for (int i = 0; i < U; ++i) {
            hv = fmaf(uu, hv, va[i]);
            hv = hv > 0.f ? hv : 0.f;
            p[(size_t)(t0 + i) * H] = f2bf(hv);
        }
        if (t0 + 2 * U < L) {
#pragma unroll
            for (int i = 0; i < U; ++i) va[i] = bf2f(p[(size_t)(t0 + 2 * U + i) * H]);
        }
#pragma unroll
        for (int i = 0; i < U; ++i) {
            hv = fmaf(uu, hv, vb[i]);
            hv = hv > 0.f ? hv : 0.f;
            p[(size_t)(t0 + U + i) * H] = f2bf(hv);
        }
    }
}

static inline void run_scan(unsigned short* buf, const float* u,
                            float* Csum, float* Asum, float* hin,
                            int Bc, int T, int H, hipStream_t stream) {
    const int nseg = Bc * S_SEG * H;
    scan_pass1<<<nseg / 256, 256, 0, stream>>>(buf, u, Csum, Asum, T, H);
    scan_boundary<<<Bc * H / 256, 256, 0, stream>>>(Csum, Asum, u, hin, T, H);
    scan_pass2<<<nseg / 256, 256, 0, stream>>>(buf, u, hin, T, H);
}

extern "C" void kernel_launch(void* const* d_in, const int* in_sizes, int n_in,
                              void* d_out, int out_size, void* d_ws, size_t ws_size,
                              hipStream_t stream) {
    const float* x   = (const float*)d_in[0];
    const float* W0  = (const float*)d_in[1];
    const float* bl0 = (const float*)d_in[2];
    const float* u0  = (const float*)d_in[3];
    const float* bb0 = (const float*)d_in[4];
    const float* W1  = (const float*)d_in[5];
    const float* bl1 = (const float*)d_in[6];
    const float* u1  = (const float*)d_in[7];
    const float* bb1 = (const float*)d_in[8];
    const float* fcW = (const float*)d_in[9];
    const float* fcb = (const float*)d_in[10];

    const int B = 64, T = 2048, Din = 128, H = 512, Dout = 128;

    const size_t szW0 = (size_t)H * Din * 2;
    const size_t szW1 = (size_t)H * H * 2;
    const size_t szFc = (size_t)Dout * H * 2;
    const size_t wfix = szW0 + szW1 + szFc;

    int Bc = B;
    while (Bc > 1) {
        const size_t szBuf  = (size_t)Bc * T * H * 2;
        const size_t szSumm = 3 * (size_t)Bc * S_SEG * H * 4;
        if (wfix + 2 * szBuf + szSumm <= ws_size) break;
        Bc >>= 1;
    }
    const int Mc = Bc * T;

    char* p = (char*)d_ws;
    unsigned short* W0b  = (unsigned short*)p;  p += szW0;
    unsigned short* W1b  = (unsigned short*)p;  p += szW1;
    unsigned short* fcWb = (unsigned short*)p;  p += szFc;
    unsigned short* buf0 = (unsigned short*)p;  p += (size_t)Mc * H * 2;
    unsigned short* R    = (unsigned short*)p;  p += (size_t)Mc * H * 2; // xc, then buf1
    float* Csum = (float*)p;                    p += (size_t)Bc * S_SEG * H * 4;
    float* Asum = (float*)p;                    p += (size_t)Bc * S_SEG * H * 4;
    float* hin  = (float*)p;

    cast_to_bf16<<<(H * Din / 4) / 256, 256, 0, stream>>>((const float4*)W0, (ushort4*)W0b, H * Din / 4);
    cast_to_bf16<<<(H * H / 4) / 256, 256, 0, stream>>>((const float4*)W1, (ushort4*)W1b, H * H / 4);
    cast_to_bf16<<<(Dout * H / 4) / 256, 256, 0, stream>>>((const float4*)fcW, (ushort4*)fcWb, Dout * H / 4);

    const dim3 blk(256);
    for (int b0 = 0; b0 < B; b0 += Bc) {
        const float* xchunk = x + (size_t)b0 * T * Din;
        float* outchunk = (float*)d_out + (size_t)b0 * T * Dout;
        unsigned short* xc   = R;            // [Mc, Din] bf16
        unsigned short* buf1 = R;            // [Mc, H] bf16 (after xc is dead)

        const int n4 = Mc * Din / 4;
        cast_to_bf16<<<n4 / 256, blk, 0, stream>>>((const float4*)xchunk, (ushort4*)xc, n4);

        // layer 0
        gemm_bt<<<dim3(H / 128, Mc / 128), blk, 0, stream>>>(
            xc, W0b, buf0, nullptr, bl0, bb0, Mc, H, Din);
        run_scan(buf0, u0, Csum, Asum, hin, Bc, T, H, stream);

        // layer 1 (buf1 overwrites xc region; xc dead after GEMM0)
        gemm_bt<<<dim3(H / 128, Mc / 128), blk, 0, stream>>>(
            buf0, W1b, buf1, nullptr, bl1, bb1, Mc, H, H);
        run_scan(buf1, u1, Csum, Asum, hin, Bc, T, H, stream);

        // FC
        gemm_bt<<<dim3(Dout / 128, Mc / 128), blk, 0, stream>>>(
            buf1, fcWb, nullptr, outchunk, fcb, nullptr, Mc, Dout, H);
    }
}

// Round 5
// 508.622 us; speedup vs baseline: 1.4049x; 1.0053x over previous
//
#include <hip/hip_runtime.h>
#include <hip/hip_bf16.h>
#include <stdint.h>

// ---------- bf16 helpers (bit-level, RNE) ----------
__device__ __forceinline__ float bf2f(unsigned short u) {
    return __uint_as_float(((unsigned int)u) << 16);
}
__device__ __forceinline__ unsigned short f2bf(float f) {
    unsigned int x = __float_as_uint(f);
    unsigned int r = (x + 0x7fffu + ((x >> 16) & 1u)) >> 16;
    return (unsigned short)r;
}

typedef __attribute__((ext_vector_type(8))) __bf16 bf16x8;
typedef __attribute__((ext_vector_type(4))) float f32x4;

__device__ __forceinline__ void gload_lds16(const void* g, void* l) {
    __builtin_amdgcn_global_load_lds(
        (const __attribute__((address_space(1))) unsigned int*)g,
        (__attribute__((address_space(3))) unsigned int*)l,
        16, 0, 0);
}

// ---------- cast fp32 -> bf16 (vectorized) ----------
__global__ void cast_to_bf16(const float4* __restrict__ in,
                             ushort4* __restrict__ out, int n4) {
    int i = blockIdx.x * blockDim.x + threadIdx.x;
    if (i < n4) {
        float4 v = in[i];
        ushort4 o;
        o.x = f2bf(v.x); o.y = f2bf(v.y); o.z = f2bf(v.z); o.w = f2bf(v.w);
        out[i] = o;
    }
}

// ---------- bf16 GEMM: C[M,N] = A[M,K] * B[N,K]^T + bias ----------
// BK=32 (64B LDS rows) + XOR chunk-swizzle SWZ(row)=(row>>1)&3:
//   physical 16B-chunk = logical chunk ^ SWZ(row).
// Store side: gload_lds dest is linear, so the SOURCE global address is
// pre-swizzled (rule #21); read side applies the same XOR. Fragment reads
// then hit all 8 bank-quads per 8 rows -> b128 floor (~8cy), no conflicts.
__global__ __launch_bounds__(256, 4)
void gemm_bt(const unsigned short* __restrict__ A,
             const unsigned short* __restrict__ B,
             unsigned short* __restrict__ Obf,
             float* __restrict__ Of32,
             const float* __restrict__ bias0,
             const float* __restrict__ bias1,
             int M, int N, int K)
{
    constexpr int BM = 128, BN = 128, BK = 32;
    __shared__ alignas(16) unsigned short Al[2][BM][BK]; // 8KB x2
    __shared__ alignas(16) unsigned short Bl[2][BN][BK]; // 8KB x2

    const int tid  = threadIdx.x;
    const int wave = tid >> 6;
    const int lane = tid & 63;
    const int wr   = wave >> 1;
    const int wc   = wave & 1;

    // XCD-chunk swizzle (bijective; all our grids have nwg % 8 == 0)
    const int nwg = gridDim.x * gridDim.y;
    int lid = blockIdx.y * gridDim.x + blockIdx.x;
    if ((nwg & 7) == 0) lid = (lid & 7) * (nwg >> 3) + (lid >> 3);
    const int n0 = (lid % gridDim.x) * BN;
    const int m0 = (lid / gridDim.x) * BM;

    const int lrow = lane >> 2;                               // row within 16-row stripe
    const int lcol = ((lane & 3) ^ ((lane >> 3) & 3)) * 8;    // swizzled source chunk

    auto stage = [&](int buf, int kt) {
        const int k0 = kt * BK;
#pragma unroll
        for (int r = 0; r < 2; ++r) {
            const int srow = wave * 32 + r * 16;
            gload_lds16(A + (size_t)(m0 + srow + lrow) * K + k0 + lcol,
                        &Al[buf][srow][0]);
            gload_lds16(B + (size_t)(n0 + srow + lrow) * K + k0 + lcol,
                        &Bl[buf][srow][0]);
        }
    };

    f32x4 acc[4][4] = {};

    // swizzled read chunk: logical k-group (lane>>4) ^ SWZ(row), row ≡ lane&15 (mod 16)
    const int ko = (((lane >> 4) ^ ((lane >> 1) & 3)) * 8);
    const int ra = wr * 64 + (lane & 15);
    const int rb = wc * 64 + (lane & 15);

    const int nt = K / BK;
    stage(0, 0);
    for (int kt = 0; kt < nt; ++kt) {
        const int cur = kt & 1;
        __syncthreads();                 // tile kt ready
        if (kt + 1 < nt) stage(cur ^ 1, kt + 1);

        bf16x8 af[4], bfr[4];
#pragma unroll
        for (int m = 0; m < 4; ++m)
            af[m] = *(const bf16x8*)&Al[cur][ra + m * 16][ko];
#pragma unroll
        for (int n = 0; n < 4; ++n)
            bfr[n] = *(const bf16x8*)&Bl[cur][rb + n * 16][ko];
#pragma unroll
        for (int m = 0; m < 4; ++m)
#pragma unroll
            for (int n = 0; n < 4; ++n)
                acc[m][n] = __builtin_amdgcn_mfma_f32_16x16x32_bf16(
                    af[m], bfr[n], acc[m][n], 0, 0, 0);
    }

    // epilogue: C/D layout col = lane&15, row = (lane>>4)*4 + i
    const int colb = n0 + wc * 64;
    const int rowb = m0 + wr * 64 + (lane >> 4) * 4;
#pragma unroll
    for (int n = 0; n < 4; ++n) {
        const int col = colb + n * 16 + (lane & 15);
        float bs = 0.f;
        if (bias0) bs += bias0[col];
        if (bias1) bs += bias1[col];
#pragma unroll
        for (int m = 0; m < 4; ++m) {
#pragma unroll
            for (int i = 0; i < 4; ++i) {
                const int row = rowb + m * 16 + i;
                const float v = acc[m][n][i] + bs;
                if (Obf) Obf[(size_t)row * N + col] = f2bf(v);
                else     Of32[(size_t)row * N + col] = v;
            }
        }
    }
}

// ================= segmented parallel IndRNN scan =================
// h_t = relu(p_t + u*h_{t-1}), u >= 0. Composition f(h)=max(C, A + u^L h)
// is associative on h>=0:  C' = max(0, p + u*C), A' = p + u*A.
constexpr int S_SEG = 16;

__global__ __launch_bounds__(256)
void scan_pass1(const unsigned short* __restrict__ proj,
                const float* __restrict__ u,
                float* __restrict__ Csum, float* __restrict__ Asum,
                int T, int H)
{
    const int L = T / S_SEG;
    const int gid = blockIdx.x * blockDim.x + threadIdx.x;
    const int h  = gid % H;
    const int bs = gid / H;
    const int s  = bs % S_SEG;
    const int b  = bs / S_SEG;
    const float uu = u[h];
    const unsigned short* p = proj + ((size_t)b * T + (size_t)s * L) * H + h;

    float C = 0.f, A = 0.f;
    constexpr int U = 8;
    float va[U], vb[U];
#pragma unroll
    for (int i = 0; i < U; ++i) va[i] = bf2f(p[(size_t)i * H]);
    for (int t0 = 0; t0 < L; t0 += 2 * U) {
#pragma unroll
        for (int i = 0; i < U; ++i) vb[i] = bf2f(p[(size_t)(t0 + U + i) * H]);
#pragma unroll
        for (int i = 0; i < U; ++i) {
            C = fmaf(uu, C, va[i]); C = C > 0.f ? C : 0.f;
            A = fmaf(uu, A, va[i]);
        }
        if (t0 + 2 * U < L) {
#pragma unroll
            for (int i = 0; i < U; ++i) va[i] = bf2f(p[(size_t)(t0 + 2 * U + i) * H]);
        }
#pragma unroll
        for (int i = 0; i < U; ++i) {
            C = fmaf(uu, C, vb[i]); C = C > 0.f ? C : 0.f;
            A = fmaf(uu, A, vb[i]);
        }
    }
    Csum[gid] = C;
    Asum[gid] = A;
}

__global__ __launch_bounds__(256)
void scan_boundary(const float* __restrict__ Csum, const float* __restrict__ Asum,
                   const float* __restrict__ u,
                   float* __restrict__ hin, int T, int H)
{
    const int gid = blockIdx.x * blockDim.x + threadIdx.x; // b*H + h
    const int h = gid % H;
    const int b = gid / H;
    const int L = T / S_SEG;
    const float W = powf(u[h], (float)L);
    float Cv[S_SEG], Av[S_SEG];
#pragma unroll
    for (int s = 0; s < S_SEG; ++s) {
        Cv[s] = Csum[((size_t)b * S_SEG + s) * H + h];
        Av[s] = Asum[((size_t)b * S_SEG + s) * H + h];
    }
    float hr = 0.f;
#pragma unroll
    for (int s = 0; s < S_SEG; ++s) {
        hin[((size_t)b * S_SEG + s) * H + h] = hr;
        const float t = fmaf(W, hr, Av[s]);
        hr = Cv[s] > t ? Cv[s] : t;
    }
}

__global__ __launch_bounds__(256)
void scan_pass2(unsigned short* __restrict__ proj,
                const float* __restrict__ u,
                const float* __restrict__ hin,
                int T, int H)
{
    const int L = T / S_SEG;
    const int gid = blockIdx.x * blockDim.x + threadIdx.x;
    const int h  = gid % H;
    const int bs = gid / H;
    const int s  = bs % S_SEG;
    const int b  = bs / S_SEG;
    const float uu = u[h];
    unsigned short* p = proj + ((size_t)b * T + (size_t)s * L) * H + h;
    float hv = hin[gid];

    constexpr int U = 8;
    float va[U], vb[U];
#pragma unroll
    for (int i = 0; i < U; ++i) va[i] = bf2f(p[(size_t)i * H]);
    for (int t0 = 0; t0 < L; t0 += 2 * U) {
#pragma unroll
        for (int i = 0; i < U; ++i) vb[i] = bf2f(p[(size_t)(t0 + U + i) * H]);
#pragma unroll
        for (int i = 0; i < U; ++i) {
            hv = fmaf(uu, hv, va[i]);
            hv = hv > 0.f ? hv : 0.f;
            p[(size_t)(t0 + i) * H] = f2bf(hv);
        }
        if (t0 + 2 * U < T / S_SEG) {
#pragma unroll
            for (int i = 0; i < U; ++i) va[i] = bf2f(p[(size_t)(t0 + 2 * U + i) * H]);
        }
#pragma unroll
        for (int i = 0; i < U; ++i) {
            hv = fmaf(uu, hv, vb[i]);
            hv = hv > 0.f ? hv : 0.f;
            p[(size_t)(t0 + U + i) * H] = f2bf(hv);
        }
    }
}

static inline void run_scan(unsigned short* buf, const float* u,
                            float* Csum, float* Asum, float* hin,
                            int Bc, int T, int H, hipStream_t stream) {
    const int nseg = Bc * S_SEG * H;
    scan_pass1<<<nseg / 256, 256, 0, stream>>>(buf, u, Csum, Asum, T, H);
    scan_boundary<<<Bc * H / 256, 256, 0, stream>>>(Csum, Asum, u, hin, T, H);
    scan_pass2<<<nseg / 256, 256, 0, stream>>>(buf, u, hin, T, H);
}

extern "C" void kernel_launch(void* const* d_in, const int* in_sizes, int n_in,
                              void* d_out, int out_size, void* d_ws, size_t ws_size,
                              hipStream_t stream) {
    const float* x   = (const float*)d_in[0];
    const float* W0  = (const float*)d_in[1];
    const float* bl0 = (const float*)d_in[2];
    const float* u0  = (const float*)d_in[3];
    const float* bb0 = (const float*)d_in[4];
    const float* W1  = (const float*)d_in[5];
    const float* bl1 = (const float*)d_in[6];
    const float* u1  = (const float*)d_in[7];
    const float* bb1 = (const float*)d_in[8];
    const float* fcW = (const float*)d_in[9];
    const float* fcb = (const float*)d_in[10];

    const int B = 64, T = 2048, Din = 128, H = 512, Dout = 128;

    const size_t szW0 = (size_t)H * Din * 2;
    const size_t szW1 = (size_t)H * H * 2;
    const size_t szFc = (size_t)Dout * H * 2;
    const size_t wfix = szW0 + szW1 + szFc;

    int Bc = B;
    while (Bc > 1) {
        const size_t szBuf  = (size_t)Bc * T * H * 2;
        const size_t szSumm = 3 * (size_t)Bc * S_SEG * H * 4;
        if (wfix + 2 * szBuf + szSumm <= ws_size) break;
        Bc >>= 1;
    }
    const int Mc = Bc * T;

    char* p = (char*)d_ws;
    unsigned short* W0b  = (unsigned short*)p;  p += szW0;
    unsigned short* W1b  = (unsigned short*)p;  p += szW1;
    unsigned short* fcWb = (unsigned short*)p;  p += szFc;
    unsigned short* buf0 = (unsigned short*)p;  p += (size_t)Mc * H * 2;
    unsigned short* R    = (unsigned short*)p;  p += (size_t)Mc * H * 2; // xc, then buf1
    float* Csum = (float*)p;                    p += (size_t)Bc * S_SEG * H * 4;
    float* Asum = (float*)p;                    p += (size_t)Bc * S_SEG * H * 4;
    float* hin  = (float*)p;

    cast_to_bf16<<<(H * Din / 4) / 256, 256, 0, stream>>>((const float4*)W0, (ushort4*)W0b, H * Din / 4);
    cast_to_bf16<<<(H * H / 4) / 256, 256, 0, stream>>>((const float4*)W1, (ushort4*)W1b, H * H / 4);
    cast_to_bf16<<<(Dout * H / 4) / 256, 256, 0, stream>>>((const float4*)fcW, (ushort4*)fcWb, Dout * H / 4);

    const dim3 blk(256);
    for (int b0 = 0; b0 < B; b0 += Bc) {
        const float* xchunk = x + (size_t)b0 * T * Din;
        float* outchunk = (float*)d_out + (size_t)b0 * T * Dout;
        unsigned short* xc   = R;            // [Mc, Din] bf16
        unsigned short* buf1 = R;            // [Mc, H] bf16 (after xc is dead)

        const int n4 = Mc * Din / 4;
        cast_to_bf16<<<n4 / 256, blk, 0, stream>>>((const float4*)xchunk, (ushort4*)xc, n4);

        // layer 0
        gemm_bt<<<dim3(H / 128, Mc / 128), blk, 0, stream>>>(
            xc, W0b, buf0, nullptr, bl0, bb0, Mc, H, Din);
        run_scan(buf0, u0, Csum, Asum, hin, Bc, T, H, stream);

        // layer 1 (buf1 overwrites xc region; xc dead after GEMM0)
        gemm_bt<<<dim3(H / 128, Mc / 128), blk, 0, stream>>>(
            buf0, W1b, buf1, nullptr, bl1, bb1, Mc, H, H);
        run_scan(buf1, u1, Csum, Asum, hin, Bc, T, H, stream);

        // FC
        gemm_bt<<<dim3(Dout / 128, Mc / 128), blk, 0, stream>>>(
            buf1, fcWb, nullptr, outchunk, fcb, nullptr, Mc, Dout, H);
    }
}